// Round 11
// baseline (370.638 us; speedup 1.0000x reference)
//
#include <hip/hip_runtime.h>
#include <hip/hip_bf16.h>
#include <cstdint>
#include <cstddef>

constexpr int TPB = 256;
constexpr int SCAN_B = 1024;
constexpr int NB   = 128;      // buckets for CSR build
constexpr int BSH  = 10;       // nodes per bucket = 1024
constexpr int NPB  = 1 << BSH;
constexpr int EPB  = 4096;     // edges per block in bucket passes
constexpr int LP   = 136;      // padded LDS row stride (shorts): 272B, 16B-aligned, 2-way-conflict only
using bf16x8 = __attribute__((ext_vector_type(8))) short;
using f32x4  = __attribute__((ext_vector_type(4))) float;

static inline int cdiv(int a, int b) { return (a + b - 1) / b; }

__device__ __forceinline__ float bf2f(short u) {
  return __uint_as_float(((unsigned int)(unsigned short)u) << 16);
}
__device__ __forceinline__ short f2bf(float f) {  // RNE
  unsigned int u = __float_as_uint(f);
  return (short)((u + 0x7FFF + ((u >> 16) & 1)) >> 16);
}

// ---------- CSR build: zero global atomics ----------

__global__ __launch_bounds__(256)
void bucket_hist_kernel(const int* __restrict__ dst, int* __restrict__ bh,
                        int e_cnt, int n_blk) {
  __shared__ int h[NB];
  int tid = threadIdx.x;
  if (tid < NB) h[tid] = 0;
  __syncthreads();
  int base = blockIdx.x * EPB;
  for (int i = tid; i < EPB; i += TPB) {
    int e = base + i;
    if (e < e_cnt) atomicAdd(&h[dst[e] >> BSH], 1);
  }
  __syncthreads();
  if (tid < NB) bh[tid * n_blk + blockIdx.x] = h[tid];
}

__global__ __launch_bounds__(SCAN_B)
void scan_block_kernel(const int* __restrict__ counts, int* __restrict__ rowptr,
                       int* __restrict__ bsum, int n) {
  __shared__ int wsum[16];
  const int tid = threadIdx.x;
  const int i = blockIdx.x * SCAN_B + tid;
  const int lane = tid & 63;
  const int w = tid >> 6;
  int v = (i < n) ? counts[i] : 0;
  int s = v;
  #pragma unroll
  for (int off = 1; off < 64; off <<= 1) {
    int t = __shfl_up(s, off, 64);
    if (lane >= off) s += t;
  }
  if (lane == 63) wsum[w] = s;
  __syncthreads();
  if (tid < 16) {
    int ws_ = wsum[tid];
    #pragma unroll
    for (int off = 1; off < 16; off <<= 1) {
      int t = __shfl_up(ws_, off, 64);
      if (tid >= off) ws_ += t;
    }
    wsum[tid] = ws_;
  }
  __syncthreads();
  int woff = (w == 0) ? 0 : wsum[w - 1];
  if (i < n) rowptr[i] = woff + s - v;
  if (tid == SCAN_B - 1) bsum[blockIdx.x] = woff + s;
}

// merged carry-scan + offset-add: every block redundantly scans bsum (nb<=128) in LDS
__global__ __launch_bounds__(256)
void scan_fin_kernel(int* __restrict__ rowptr, const int* __restrict__ bsum,
                     int nb, int n, int total) {
  __shared__ int sb[128];
  int tid = threadIdx.x;
  if (tid == 0) {
    int run = 0;
    for (int b = 0; b < nb; ++b) { sb[b] = run; run += bsum[b]; }
  }
  __syncthreads();
  int i = blockIdx.x * TPB + tid;
  if (i < n) rowptr[i] += sb[i / SCAN_B];
  if (i == 0) rowptr[n] = total;
}

__global__ __launch_bounds__(256)
void bucket_scatter_kernel(const int* __restrict__ src, const int* __restrict__ dst,
                           const int* __restrict__ eoff, unsigned int* __restrict__ ebuf,
                           int e_cnt, int n_blk) {
  __shared__ int cur[NB];
  int tid = threadIdx.x;
  if (tid < NB) cur[tid] = eoff[tid * n_blk + blockIdx.x];
  __syncthreads();
  int base = blockIdx.x * EPB;
  for (int i = tid; i < EPB; i += TPB) {
    int e = base + i;
    if (e < e_cnt) {
      int d = dst[e];
      int b = d >> BSH;
      int pos = atomicAdd(&cur[b], 1);  // LDS atomic
      ebuf[pos] = ((unsigned int)src[e] << BSH) | (unsigned int)(d & (NPB - 1));
    }
  }
}

// per-bucket node hist + dinv, no global atomics
__global__ __launch_bounds__(256)
void node_hist_kernel(const unsigned int* __restrict__ ebuf, const int* __restrict__ eoff,
                      int* __restrict__ counts, float* __restrict__ dinv,
                      int n_blk, int n_nodes) {
  __shared__ int nh[NPB];
  int b = blockIdx.x;
  for (int i = threadIdx.x; i < NPB; i += TPB) nh[i] = 0;
  __syncthreads();
  int wb = eoff[b * n_blk];
  int we = eoff[(b + 1) * n_blk];
  for (int i = wb + threadIdx.x; i < we; i += TPB)
    atomicAdd(&nh[ebuf[i] & (NPB - 1)], 1);  // LDS atomic
  __syncthreads();
  int nbase = b << BSH;
  for (int i = threadIdx.x; i < NPB; i += TPB) {
    int node = nbase + i;
    if (node < n_nodes) {
      counts[node] = nh[i];
      dinv[node] = rsqrtf((float)nh[i] + 1.0f);  // +1 self-loop
    }
  }
}

__global__ __launch_bounds__(256)
void final_scatter_kernel(const unsigned int* __restrict__ ebuf, const int* __restrict__ eoff,
                          const int* __restrict__ rowptr, int* __restrict__ csr_src,
                          int n_blk, int n_nodes) {
  __shared__ int cur[NPB];
  int b = blockIdx.x;
  int nbase = b << BSH;
  for (int i = threadIdx.x; i < NPB; i += TPB) {
    int node = nbase + i;
    cur[i] = (node < n_nodes) ? rowptr[node] : 0;
  }
  __syncthreads();
  int wb = eoff[b * n_blk];
  int we = eoff[(b + 1) * n_blk];
  for (int i = wb + threadIdx.x; i < we; i += TPB) {
    unsigned int p = ebuf[i];
    int pos = atomicAdd(&cur[p & (NPB - 1)], 1);  // LDS atomic
    csr_src[pos] = (int)(p >> BSH);
  }
}

// ---------- prep ----------

// one kernel: W1p pad + combined biases (block 0), W2T (blocks 1..64),
// combined WcaT/WcbT = (Wfc@Wd1a/b)^T bf16 (blocks 65..128)
__global__ __launch_bounds__(256)
void prep_weights_kernel(const float* __restrict__ W1, const float* __restrict__ W2,
                         const float* __restrict__ Wfc, const float* __restrict__ bfc,
                         const float* __restrict__ Wd1, const float* __restrict__ bd1,
                         float* __restrict__ W1p, unsigned short* __restrict__ W2T,
                         unsigned short* __restrict__ WcaT, unsigned short* __restrict__ WcbT,
                         float* __restrict__ bca, float* __restrict__ bcb) {
  int b = blockIdx.x;
  int tid = threadIdx.x;
  if (b == 0) {
    for (int i = tid; i < 8 * 128; i += TPB)
      W1p[i] = (i < 7 * 128) ? W1[i] : 0.0f;
    int j = tid & 127;
    int which = tid >> 7;
    float acc = which ? 0.0f : bd1[j];
    int mo = which ? 64 : 0;
    #pragma unroll 8
    for (int m = 0; m < 64; ++m) acc = fmaf(bfc[m], Wd1[(mo + m) * 128 + j], acc);
    if (which) bcb[j] = acc; else bca[j] = acc;
  } else if (b <= 64) {
    int idx = (b - 1) * 256 + tid;   // 16384 = W2T elems
    int n = idx >> 7, k = idx & 127;
    W2T[idx] = (unsigned short)f2bf(W2[k * 128 + n]);  // W2T[n][k] = W2[k][n]
  } else {
    int idx = (b - 65) * 256 + tid;  // 16384 combined outputs
    int j = idx >> 7, k = idx & 127;
    float accA = 0.0f, accB = 0.0f;
    #pragma unroll 8
    for (int m = 0; m < 64; ++m) {
      float w = Wfc[k * 64 + m];
      accA = fmaf(w, Wd1[m * 128 + j], accA);
      accB = fmaf(w, Wd1[(64 + m) * 128 + j], accB);
    }
    WcaT[j * 128 + k] = (unsigned short)f2bf(accA);  // [N][K]
    WcbT[j * 128 + k] = (unsigned short)f2bf(accB);
  }
}

// ---------- graph pipeline ----------

// aggx = A_hat @ x (reads x[n,7] directly, feature 7 = 0); 8 lanes/node, 2-chain
__global__ __launch_bounds__(256)
void agg_x_kernel(const int* __restrict__ rowptr, const int* __restrict__ csr_src,
                  const float* __restrict__ dinv, const float* __restrict__ x,
                  float* __restrict__ aggx, int n_nodes) {
  int gid = blockIdx.x * TPB + threadIdx.x;
  int node = gid >> 3;
  int f = gid & 7;
  if (node >= n_nodes) return;
  bool live = (f < 7);
  float dn = dinv[node];
  float acc0 = live ? x[(size_t)node * 7 + f] * dn * dn : 0.0f;
  float acc1 = 0.0f;
  int beg = rowptr[node], end = rowptr[node + 1];
  int i = beg;
  for (; i + 1 < end; i += 2) {
    int s0 = csr_src[i];
    int s1 = csr_src[i + 1];
    float w0 = dinv[s0] * dn;
    float w1 = dinv[s1] * dn;
    if (live) {
      acc0 = fmaf(x[(size_t)s0 * 7 + f], w0, acc0);
      acc1 = fmaf(x[(size_t)s1 * 7 + f], w1, acc1);
    }
  }
  if (i < end && live) {
    int s = csr_src[i];
    acc0 = fmaf(x[(size_t)s * 7 + f], dinv[s] * dn, acc0);
  }
  aggx[(size_t)node * 8 + f] = acc0 + acc1;
}

// Register-tiled SGEMM (layer-1 only: K=8); bf16 out, scale[row] after relu
template<int K, int CO>
__global__ __launch_bounds__(256)
void mm_tiled(const float* __restrict__ in, const float* __restrict__ W,
              const float* __restrict__ bias, const float* __restrict__ scale,
              unsigned short* __restrict__ outv, int n_rows) {
  constexpr int BM = 64;
  constexpr int BK = K;
  constexpr int SS = BK + 1 + (BK & 1);
  constexpr int TM = 4;
  constexpr int TN = CO / 16;
  __shared__ float s_in[BM][SS];
  __shared__ float s_w[BK][CO];
  const int tid = threadIdx.x;
  const int base = blockIdx.x * BM;
  const int tr = tid >> 4;
  const int tc = tid & 15;

  float acc[TM][TN];
  #pragma unroll
  for (int m = 0; m < TM; ++m)
    #pragma unroll
    for (int n = 0; n < TN; ++n) acc[m][n] = 0.0f;

  {
    constexpr int F4 = BM * (BK / 4);
    #pragma unroll
    for (int t = tid; t < F4; t += TPB) {
      int r = t / (BK / 4), c4 = t % (BK / 4);
      int row = base + r;
      float4 v = make_float4(0.f, 0.f, 0.f, 0.f);
      if (row < n_rows) v = *(const float4*)(in + (size_t)row * K + c4 * 4);
      s_in[r][c4 * 4 + 0] = v.x;
      s_in[r][c4 * 4 + 1] = v.y;
      s_in[r][c4 * 4 + 2] = v.z;
      s_in[r][c4 * 4 + 3] = v.w;
    }
    constexpr int WF4 = BK * CO / 4;
    #pragma unroll
    for (int t = tid; t < WF4; t += TPB)
      *(float4*)(&s_w[0][0] + t * 4) = *(const float4*)(W + t * 4);
  }
  __syncthreads();

  #pragma unroll
  for (int kk = 0; kk < BK; ++kk) {
    float a[TM], b[TN];
    #pragma unroll
    for (int m = 0; m < TM; ++m) a[m] = s_in[tr * TM + m][kk];
    #pragma unroll
    for (int n = 0; n < TN; ++n) b[n] = s_w[kk][tc + 16 * n];
    #pragma unroll
    for (int m = 0; m < TM; ++m)
      #pragma unroll
      for (int n = 0; n < TN; ++n) acc[m][n] = fmaf(a[m], b[n], acc[m][n]);
  }

  #pragma unroll
  for (int m = 0; m < TM; ++m) {
    int row = base + tr * TM + m;
    if (row < n_rows) {
      float sc = scale[row];
      #pragma unroll
      for (int n = 0; n < TN; ++n) {
        int j = tc + 16 * n;
        float v = fmaxf(acc[m][n] + bias[j], 0.0f) * sc;
        outv[(size_t)row * CO + j] = (unsigned short)f2bf(v);
      }
    }
  }
}

// Fused layer-2: gather (g1 into LDS) + 128x128 MFMA GEMM + bias + relu -> h2 bf16.
// Block = 64 nodes, 4 waves x 16 nodes. W2T staged in LDS (padded stride LP).
// Numerics identical to gather4 -> mm_mfma: same f2bf pack of g1.
__global__ __launch_bounds__(256)
void gcn_fused_kernel(const int* __restrict__ rowptr, const int* __restrict__ csr_src,
                      const float* __restrict__ dinv, const uint4* __restrict__ h1s,
                      const unsigned short* __restrict__ W2T, const float* __restrict__ b2,
                      unsigned short* __restrict__ h2, int n_nodes) {
  __shared__ unsigned short g1s[64 * LP];
  __shared__ unsigned short w2s[128 * LP];
  const int tid = threadIdx.x;
  // stage W2T [128][128] -> padded LDS
  for (int i = tid; i < 128 * 16; i += TPB) {
    int row = i >> 4, seg = i & 15;
    *(uint4*)&w2s[row * LP + seg * 8] = *(const uint4*)(W2T + (size_t)row * 128 + seg * 8);
  }
  __syncthreads();

  const int lane = tid & 63;
  const int w = tid >> 6;
  const int qtr = lane >> 4;
  const int l = lane & 15;
  const int base = blockIdx.x * 64;

  // ---- gather phase: wave w fills g1s rows w*16 .. w*16+15 (wave-private) ----
  for (int nn = 0; nn < 16; ++nn) {
    int node = base + w * 16 + nn;
    if (node >= n_nodes) break;
    float acc[8];
    #pragma unroll
    for (int j = 0; j < 8; ++j) acc[j] = 0.0f;
    auto addv = [&](uint4 v) {
      unsigned int u[4] = {v.x, v.y, v.z, v.w};
      #pragma unroll
      for (int p = 0; p < 4; ++p) {
        acc[2 * p]     += __uint_as_float(u[p] << 16);
        acc[2 * p + 1] += __uint_as_float(u[p] & 0xffff0000u);
      }
    };
    if (qtr == 0) addv(h1s[(size_t)node * 16 + l]);  // self term
    int beg = rowptr[node], end = rowptr[node + 1];
    int i = beg + qtr;
    for (; i + 4 < end; i += 8) {
      int s0 = csr_src[i];
      int s1 = csr_src[i + 4];
      uint4 v0 = h1s[(size_t)s0 * 16 + l];
      uint4 v1 = h1s[(size_t)s1 * 16 + l];
      addv(v0);
      addv(v1);
    }
    if (i < end) addv(h1s[(size_t)csr_src[i] * 16 + l]);
    #pragma unroll
    for (int j = 0; j < 8; ++j) {
      acc[j] += __shfl_xor(acc[j], 16, 64);
      acc[j] += __shfl_xor(acc[j], 32, 64);
    }
    if (qtr == 0) {
      float dn = dinv[node];
      unsigned int wv[4];
      #pragma unroll
      for (int p = 0; p < 4; ++p) {
        unsigned int lo = (unsigned int)(unsigned short)f2bf(acc[2 * p] * dn);
        unsigned int hi = (unsigned int)(unsigned short)f2bf(acc[2 * p + 1] * dn);
        wv[p] = lo | (hi << 16);
      }
      uint4 o; o.x = wv[0]; o.y = wv[1]; o.z = wv[2]; o.w = wv[3];
      *(uint4*)&g1s[(w * 16 + nn) * LP + l * 8] = o;
    }
  }
  // wave-private LDS region: no __syncthreads needed (compiler orders ds ops in-wave)

  // ---- GEMM phase: wave computes its 16-node tile x 128 cols ----
  bf16x8 afrag[4];
  #pragma unroll
  for (int ks = 0; ks < 4; ++ks)
    afrag[ks] = *(const bf16x8*)&g1s[(w * 16 + l) * LP + ks * 32 + qtr * 8];
  f32x4 acc[8];
  #pragma unroll
  for (int nt = 0; nt < 8; ++nt) acc[nt] = {0.f, 0.f, 0.f, 0.f};
  #pragma unroll
  for (int ks = 0; ks < 4; ++ks)
    #pragma unroll
    for (int nt = 0; nt < 8; ++nt) {
      bf16x8 bfrag = *(const bf16x8*)&w2s[(nt * 16 + l) * LP + ks * 32 + qtr * 8];
      acc[nt] = __builtin_amdgcn_mfma_f32_16x16x32_bf16(afrag[ks], bfrag, acc[nt], 0, 0, 0);
    }
  #pragma unroll
  for (int r = 0; r < 4; ++r) {
    int node = base + w * 16 + qtr * 4 + r;
    if (node < n_nodes) {
      #pragma unroll
      for (int nt = 0; nt < 8; ++nt) {
        float v = fmaxf(acc[nt][r] + b2[nt * 16 + l], 0.0f);
        h2[(size_t)node * 128 + nt * 16 + l] = (unsigned short)f2bf(v);
      }
    }
  }
}

// MFMA GEMM: out(bf16)[n_rows,N] = A(bf16)[n_rows,K] @ WT(bf16)[N,K]^T (+bias)(+relu)
template<int K, int N>
__global__ __launch_bounds__(256)
void mm_mfma(const unsigned short* __restrict__ A, const unsigned short* __restrict__ WT,
             const float* __restrict__ bias, unsigned short* __restrict__ out,
             int n_rows, int do_relu) {
  constexpr int KS = K / 32;
  constexpr int NT = N / 16;
  const int lane = threadIdx.x & 63;
  const int col = lane & 15;
  const int sub = lane >> 4;
  const int wid = threadIdx.x >> 6;

  bf16x8 bfrag[KS][NT];
  #pragma unroll
  for (int ks = 0; ks < KS; ++ks)
    #pragma unroll
    for (int nt = 0; nt < NT; ++nt)
      bfrag[ks][nt] = *(const bf16x8*)(WT + (size_t)(nt * 16 + col) * K + ks * 32 + sub * 8);
  float bv[NT];
  #pragma unroll
  for (int nt = 0; nt < NT; ++nt) bv[nt] = bias ? bias[nt * 16 + col] : 0.0f;

  int ntiles = (n_rows + 15) >> 4;
  int stride = gridDim.x * 4;
  for (int tile = blockIdx.x * 4 + wid; tile < ntiles; tile += stride) {
    int row_a = tile * 16 + col;
    if (row_a >= n_rows) row_a = n_rows - 1;
    bf16x8 afrag[KS];
    #pragma unroll
    for (int ks = 0; ks < KS; ++ks)
      afrag[ks] = *(const bf16x8*)(A + (size_t)row_a * K + ks * 32 + sub * 8);
    f32x4 acc[NT];
    #pragma unroll
    for (int nt = 0; nt < NT; ++nt) acc[nt] = {0.f, 0.f, 0.f, 0.f};
    #pragma unroll
    for (int ks = 0; ks < KS; ++ks)
      #pragma unroll
      for (int nt = 0; nt < NT; ++nt)
        acc[nt] = __builtin_amdgcn_mfma_f32_16x16x32_bf16(afrag[ks], bfrag[ks][nt], acc[nt], 0, 0, 0);
    #pragma unroll
    for (int r = 0; r < 4; ++r) {
      int ro = tile * 16 + sub * 4 + r;
      if (ro < n_rows) {
        #pragma unroll
        for (int nt = 0; nt < NT; ++nt) {
          float v = acc[nt][r] + bv[nt];
          if (do_relu) v = fmaxf(v, 0.0f);
          out[(size_t)ro * N + nt * 16 + col] = (unsigned short)f2bf(v);
        }
      }
    }
  }
}

// MFMA decoder: 16 queries per wave-tile. (layouts validated)
__global__ __launch_bounds__(256)
void decoder_mfma_kernel(const int* __restrict__ qsrc, const int* __restrict__ qdst,
                         const unsigned short* __restrict__ atab,
                         const unsigned short* __restrict__ btab,
                         const float* __restrict__ Wd2, const float* __restrict__ bd2,
                         const float* __restrict__ Wd3, const float* __restrict__ bd3,
                         float* __restrict__ out, int n_query) {
  const int lane = threadIdx.x & 63;
  const int col = lane & 15;
  const int sub = lane >> 4;

  bf16x8 bfrag[4][4];
  #pragma unroll
  for (int ks = 0; ks < 4; ++ks)
    #pragma unroll
    for (int nt = 0; nt < 4; ++nt) {
      bf16x8 f;
      #pragma unroll
      for (int j = 0; j < 8; ++j) {
        int k = ks * 32 + sub * 8 + j;
        int n = nt * 16 + col;
        f[j] = f2bf(Wd2[k * 64 + n]);
      }
      bfrag[ks][nt] = f;
    }
  float bd2v[4], wd3v[4];
  #pragma unroll
  for (int nt = 0; nt < 4; ++nt) {
    bd2v[nt] = bd2[nt * 16 + col];
    wd3v[nt] = Wd3[nt * 16 + col];
  }
  const float bd3s = bd3[0];

  int wave = (blockIdx.x * TPB + threadIdx.x) >> 6;
  int nwaves = gridDim.x * (TPB / 64);
  int ntiles = (n_query + 15) >> 4;
  for (int t = wave; t < ntiles; t += nwaves) {
    int qb = t << 4;
    int q = qb + col;
    if (q >= n_query) q = n_query - 1;
    int si = qsrc[q], di = qdst[q];
    const bf16x8* ar = (const bf16x8*)(atab + (size_t)si * 128);
    const bf16x8* br = (const bf16x8*)(btab + (size_t)di * 128);
    bf16x8 afrag[4];
    #pragma unroll
    for (int ks = 0; ks < 4; ++ks) {
      bf16x8 av = ar[ks * 4 + sub];
      bf16x8 bv = br[ks * 4 + sub];
      bf16x8 d;
      #pragma unroll
      for (int j = 0; j < 8; ++j)
        d[j] = f2bf(fmaxf(bf2f(av[j]) + bf2f(bv[j]), 0.0f));  // d1 = relu(a+b)
      afrag[ks] = d;
    }
    f32x4 acc[4];
    #pragma unroll
    for (int nt = 0; nt < 4; ++nt) acc[nt] = {0.f, 0.f, 0.f, 0.f};
    #pragma unroll
    for (int ks = 0; ks < 4; ++ks)
      #pragma unroll
      for (int nt = 0; nt < 4; ++nt)
        acc[nt] = __builtin_amdgcn_mfma_f32_16x16x32_bf16(afrag[ks], bfrag[ks][nt], acc[nt], 0, 0, 0);
    float part[4] = {0.f, 0.f, 0.f, 0.f};
    #pragma unroll
    for (int nt = 0; nt < 4; ++nt)
      #pragma unroll
      for (int r = 0; r < 4; ++r) {
        float v = fmaxf(acc[nt][r] + bd2v[nt], 0.0f);
        part[r] = fmaf(v, wd3v[nt], part[r]);
      }
    #pragma unroll
    for (int off = 1; off < 16; off <<= 1)
      #pragma unroll
      for (int r = 0; r < 4; ++r) part[r] += __shfl_xor(part[r], off, 64);
    if (col == 0) {
      int row0 = qb + sub * 4;
      #pragma unroll
      for (int r = 0; r < 4; ++r) {
        int qq = row0 + r;
        if (qq < n_query) out[qq] = 1.0f / (1.0f + __expf(-(part[r] + bd3s)));
      }
    }
  }
}

extern "C" void kernel_launch(void* const* d_in, const int* in_sizes, int n_in,
                              void* d_out, int out_size, void* d_ws, size_t ws_size,
                              hipStream_t stream) {
  const float* x    = (const float*)d_in[0];
  const int*   ei   = (const int*)d_in[1];
  const int*   qe   = (const int*)d_in[2];
  const float* W1   = (const float*)d_in[3];
  const float* b1   = (const float*)d_in[4];
  const float* W2   = (const float*)d_in[5];
  const float* b2   = (const float*)d_in[6];
  const float* Wfc  = (const float*)d_in[7];
  const float* bfc  = (const float*)d_in[8];
  const float* Wd1  = (const float*)d_in[9];
  const float* bd1  = (const float*)d_in[10];
  const float* Wd2  = (const float*)d_in[11];
  const float* bd2  = (const float*)d_in[12];
  const float* Wd3  = (const float*)d_in[13];
  const float* bd3  = (const float*)d_in[14];
  float* out = (float*)d_out;

  const int n_nodes = in_sizes[0] / 7;
  const int n_edges = in_sizes[1] / 2;
  const int n_query = in_sizes[2] / 2;
  const int* e_src = ei;
  const int* e_dst = ei + n_edges;
  const int* q_src = qe;
  const int* q_dst = qe + n_query;

  const int n_blk1 = cdiv(n_edges, EPB);
  const int bh_len = NB * n_blk1;
  const int n_bucket = cdiv(n_nodes, NPB);

  // ---- workspace layout ----
  char* wp = (char*)d_ws;
  auto take = [&](size_t bytes) { char* p = wp; wp += (bytes + 255) & ~size_t(255); return p; };
  float* dinv    = (float*)take((size_t)n_nodes * 4);
  int*   counts  = (int*)  take((size_t)n_nodes * 4);
  int*   rowptr  = (int*)  take((size_t)(n_nodes + 1) * 4);
  int*   bsum    = (int*)  take(512 * 4);
  int*   bh      = (int*)  take((size_t)(bh_len + 1) * 4);
  int*   eoff    = (int*)  take((size_t)(bh_len + 1) * 4);
  unsigned int* ebuf = (unsigned int*)take((size_t)n_edges * 4);
  int*   csr_src = (int*)  take((size_t)n_edges * 4);
  float* aggx    = (float*)take((size_t)n_nodes * 8 * 4);
  float* W1p     = (float*)take(8 * 128 * 4);
  unsigned short* W2T   = (unsigned short*)take(128 * 128 * 2);
  unsigned short* WcaT  = (unsigned short*)take(128 * 128 * 2);
  unsigned short* WcbT  = (unsigned short*)take(128 * 128 * 2);
  float* bca     = (float*)take(128 * 4);
  float* bcb     = (float*)take(128 * 4);
  float* bufP    = (float*)take((size_t)n_nodes * 128 * 4);
  float* bufQ    = (float*)take((size_t)n_nodes * 128 * 4);
  float* bufR    = (float*)take((size_t)n_nodes * 64 * 4);

  const int mm_blocks = cdiv(n_nodes, 64);
  const int node_blocks = cdiv(n_nodes, TPB);
  const int scan_blocks = cdiv(n_nodes, SCAN_B);
  const int escan_blocks = cdiv(bh_len, SCAN_B);
  const int mfma_blocks = min(1024, cdiv(cdiv(n_nodes, 16), 4));

  // ---- CSR build (no global atomics): 8 dispatches ----
  bucket_hist_kernel<<<n_blk1, TPB, 0, stream>>>(e_dst, bh, n_edges, n_blk1);
  scan_block_kernel<<<escan_blocks, SCAN_B, 0, stream>>>(bh, eoff, bsum, bh_len);
  scan_fin_kernel<<<cdiv(bh_len, TPB), TPB, 0, stream>>>(eoff, bsum, escan_blocks, bh_len, n_edges);
  bucket_scatter_kernel<<<n_blk1, TPB, 0, stream>>>(e_src, e_dst, eoff, ebuf, n_edges, n_blk1);
  node_hist_kernel<<<n_bucket, TPB, 0, stream>>>(ebuf, eoff, counts, dinv, n_blk1, n_nodes);
  scan_block_kernel<<<scan_blocks, SCAN_B, 0, stream>>>(counts, rowptr, bsum, n_nodes);
  scan_fin_kernel<<<node_blocks, TPB, 0, stream>>>(rowptr, bsum, scan_blocks, n_nodes, n_edges);
  final_scatter_kernel<<<n_bucket, TPB, 0, stream>>>(ebuf, eoff, rowptr, csr_src, n_blk1, n_nodes);

  // ---- prep ----
  prep_weights_kernel<<<129, TPB, 0, stream>>>(W1, W2, Wfc, bfc, Wd1, bd1,
                                               W1p, W2T, WcaT, WcbT, bca, bcb);

  // ---- layer 1: aggx = A_hat x ; h1s(bf16) = relu(aggx @ W1p + b1) * dinv ----
  agg_x_kernel<<<cdiv(n_nodes * 8, TPB), TPB, 0, stream>>>(rowptr, csr_src, dinv, x, aggx, n_nodes);
  mm_tiled<8, 128><<<mm_blocks, TPB, 0, stream>>>(aggx, W1p, b1, dinv, (unsigned short*)bufP, n_nodes);
  // bufP = h1s (bf16, prescaled)

  // ---- layer 2 (fused): h2(bf16) = relu( (A_hat h1) @ W2 + b2 ) ----
  gcn_fused_kernel<<<cdiv(n_nodes, 64), TPB, 0, stream>>>(rowptr, csr_src, dinv,
                                                          (const uint4*)bufP, W2T, b2,
                                                          (unsigned short*)bufQ, n_nodes);
  // bufQ = h2 (bf16)

  // ---- decoder tables (fc folded): atab = h2@Wca + bca ; btab = h2@Wcb + bcb ----
  unsigned short* atab = (unsigned short*)bufP;
  unsigned short* btab = (unsigned short*)bufR;
  mm_mfma<128, 128><<<mfma_blocks, TPB, 0, stream>>>((const unsigned short*)bufQ, WcaT, bca,
                                                     atab, n_nodes, 0);
  mm_mfma<128, 128><<<mfma_blocks, TPB, 0, stream>>>((const unsigned short*)bufQ, WcbT, bcb,
                                                     btab, n_nodes, 0);

  // ---- per-query decode (MFMA) ----
  decoder_mfma_kernel<<<2048, TPB, 0, stream>>>(q_src, q_dst, atab, btab, Wd2, bd2, Wd3, bd3, out, n_query);
}

// Round 12
// 305.080 us; speedup vs baseline: 1.2149x; 1.2149x over previous
//
#include <hip/hip_runtime.h>
#include <hip/hip_bf16.h>
#include <cstdint>
#include <cstddef>

constexpr int TPB = 256;
constexpr int SCAN_B = 1024;
constexpr int NB   = 128;      // buckets for CSR build
constexpr int BSH  = 10;       // nodes per bucket = 1024
constexpr int NPB  = 1 << BSH;
constexpr int EPB  = 4096;     // edges per block in bucket passes
using bf16x8 = __attribute__((ext_vector_type(8))) short;
using f32x4  = __attribute__((ext_vector_type(4))) float;

static inline int cdiv(int a, int b) { return (a + b - 1) / b; }

__device__ __forceinline__ float bf2f(short u) {
  return __uint_as_float(((unsigned int)(unsigned short)u) << 16);
}
__device__ __forceinline__ short f2bf(float f) {  // RNE
  unsigned int u = __float_as_uint(f);
  return (short)((u + 0x7FFF + ((u >> 16) & 1)) >> 16);
}

// ---------- CSR build: zero global atomics ----------

__global__ __launch_bounds__(256)
void bucket_hist_kernel(const int* __restrict__ dst, int* __restrict__ bh,
                        int e_cnt, int n_blk) {
  __shared__ int h[NB];
  int tid = threadIdx.x;
  if (tid < NB) h[tid] = 0;
  __syncthreads();
  int base = blockIdx.x * EPB;
  for (int i = tid; i < EPB; i += TPB) {
    int e = base + i;
    if (e < e_cnt) atomicAdd(&h[dst[e] >> BSH], 1);
  }
  __syncthreads();
  if (tid < NB) bh[tid * n_blk + blockIdx.x] = h[tid];
}

__global__ __launch_bounds__(SCAN_B)
void scan_block_kernel(const int* __restrict__ counts, int* __restrict__ rowptr,
                       int* __restrict__ bsum, int n) {
  __shared__ int wsum[16];
  const int tid = threadIdx.x;
  const int i = blockIdx.x * SCAN_B + tid;
  const int lane = tid & 63;
  const int w = tid >> 6;
  int v = (i < n) ? counts[i] : 0;
  int s = v;
  #pragma unroll
  for (int off = 1; off < 64; off <<= 1) {
    int t = __shfl_up(s, off, 64);
    if (lane >= off) s += t;
  }
  if (lane == 63) wsum[w] = s;
  __syncthreads();
  if (tid < 16) {
    int ws_ = wsum[tid];
    #pragma unroll
    for (int off = 1; off < 16; off <<= 1) {
      int t = __shfl_up(ws_, off, 64);
      if (tid >= off) ws_ += t;
    }
    wsum[tid] = ws_;
  }
  __syncthreads();
  int woff = (w == 0) ? 0 : wsum[w - 1];
  if (i < n) rowptr[i] = woff + s - v;
  if (tid == SCAN_B - 1) bsum[blockIdx.x] = woff + s;
}

// merged carry-scan + offset-add
__global__ __launch_bounds__(256)
void scan_fin_kernel(int* __restrict__ rowptr, const int* __restrict__ bsum,
                     int nb, int n, int total) {
  __shared__ int sb[128];
  int tid = threadIdx.x;
  if (tid == 0) {
    int run = 0;
    for (int b = 0; b < nb; ++b) { sb[b] = run; run += bsum[b]; }
  }
  __syncthreads();
  int i = blockIdx.x * TPB + tid;
  if (i < n) rowptr[i] += sb[i / SCAN_B];
  if (i == 0) rowptr[n] = total;
}

__global__ __launch_bounds__(256)
void bucket_scatter_kernel(const int* __restrict__ src, const int* __restrict__ dst,
                           const int* __restrict__ eoff, unsigned int* __restrict__ ebuf,
                           int e_cnt, int n_blk) {
  __shared__ int cur[NB];
  int tid = threadIdx.x;
  if (tid < NB) cur[tid] = eoff[tid * n_blk + blockIdx.x];
  __syncthreads();
  int base = blockIdx.x * EPB;
  for (int i = tid; i < EPB; i += TPB) {
    int e = base + i;
    if (e < e_cnt) {
      int d = dst[e];
      int b = d >> BSH;
      int pos = atomicAdd(&cur[b], 1);  // LDS atomic
      ebuf[pos] = ((unsigned int)src[e] << BSH) | (unsigned int)(d & (NPB - 1));
    }
  }
}

// per-bucket node hist + dinv, no global atomics
__global__ __launch_bounds__(256)
void node_hist_kernel(const unsigned int* __restrict__ ebuf, const int* __restrict__ eoff,
                      int* __restrict__ counts, float* __restrict__ dinv,
                      int n_blk, int n_nodes) {
  __shared__ int nh[NPB];
  int b = blockIdx.x;
  for (int i = threadIdx.x; i < NPB; i += TPB) nh[i] = 0;
  __syncthreads();
  int wb = eoff[b * n_blk];
  int we = eoff[(b + 1) * n_blk];
  for (int i = wb + threadIdx.x; i < we; i += TPB)
    atomicAdd(&nh[ebuf[i] & (NPB - 1)], 1);  // LDS atomic
  __syncthreads();
  int nbase = b << BSH;
  for (int i = threadIdx.x; i < NPB; i += TPB) {
    int node = nbase + i;
    if (node < n_nodes) {
      counts[node] = nh[i];
      dinv[node] = rsqrtf((float)nh[i] + 1.0f);  // +1 self-loop
    }
  }
}

__global__ __launch_bounds__(256)
void final_scatter_kernel(const unsigned int* __restrict__ ebuf, const int* __restrict__ eoff,
                          const int* __restrict__ rowptr, int* __restrict__ csr_src,
                          int n_blk, int n_nodes) {
  __shared__ int cur[NPB];
  int b = blockIdx.x;
  int nbase = b << BSH;
  for (int i = threadIdx.x; i < NPB; i += TPB) {
    int node = nbase + i;
    cur[i] = (node < n_nodes) ? rowptr[node] : 0;
  }
  __syncthreads();
  int wb = eoff[b * n_blk];
  int we = eoff[(b + 1) * n_blk];
  for (int i = wb + threadIdx.x; i < we; i += TPB) {
    unsigned int p = ebuf[i];
    int pos = atomicAdd(&cur[p & (NPB - 1)], 1);  // LDS atomic
    csr_src[pos] = (int)(p >> BSH);
  }
}

// ---------- prep ----------

// W1p pad + combined biases (block 0), W2T (blocks 1..64),
// combined WcaT/WcbT = (Wfc@Wd1a/b)^T bf16 (blocks 65..128)
__global__ __launch_bounds__(256)
void prep_weights_kernel(const float* __restrict__ W1, const float* __restrict__ W2,
                         const float* __restrict__ Wfc, const float* __restrict__ bfc,
                         const float* __restrict__ Wd1, const float* __restrict__ bd1,
                         float* __restrict__ W1p, unsigned short* __restrict__ W2T,
                         unsigned short* __restrict__ WcaT, unsigned short* __restrict__ WcbT,
                         float* __restrict__ bca, float* __restrict__ bcb) {
  int b = blockIdx.x;
  int tid = threadIdx.x;
  if (b == 0) {
    for (int i = tid; i < 8 * 128; i += TPB)
      W1p[i] = (i < 7 * 128) ? W1[i] : 0.0f;
    int j = tid & 127;
    int which = tid >> 7;
    float acc = which ? 0.0f : bd1[j];
    int mo = which ? 64 : 0;
    #pragma unroll 8
    for (int m = 0; m < 64; ++m) acc = fmaf(bfc[m], Wd1[(mo + m) * 128 + j], acc);
    if (which) bcb[j] = acc; else bca[j] = acc;
  } else if (b <= 64) {
    int idx = (b - 1) * 256 + tid;   // 16384 = W2T elems
    int n = idx >> 7, k = idx & 127;
    W2T[idx] = (unsigned short)f2bf(W2[k * 128 + n]);  // W2T[n][k] = W2[k][n]
  } else {
    int idx = (b - 65) * 256 + tid;  // 16384 combined outputs
    int j = idx >> 7, k = idx & 127;
    float accA = 0.0f, accB = 0.0f;
    #pragma unroll 8
    for (int m = 0; m < 64; ++m) {
      float w = Wfc[k * 64 + m];
      accA = fmaf(w, Wd1[m * 128 + j], accA);
      accB = fmaf(w, Wd1[(64 + m) * 128 + j], accB);
    }
    WcaT[j * 128 + k] = (unsigned short)f2bf(accA);  // [N][K]
    WcbT[j * 128 + k] = (unsigned short)f2bf(accB);
  }
}

// ---------- graph pipeline ----------

// aggx = A_hat @ x (reads x[n,7] directly, feature 7 = 0); 8 lanes/node, 2-chain
__global__ __launch_bounds__(256)
void agg_x_kernel(const int* __restrict__ rowptr, const int* __restrict__ csr_src,
                  const float* __restrict__ dinv, const float* __restrict__ x,
                  float* __restrict__ aggx, int n_nodes) {
  int gid = blockIdx.x * TPB + threadIdx.x;
  int node = gid >> 3;
  int f = gid & 7;
  if (node >= n_nodes) return;
  bool live = (f < 7);
  float dn = dinv[node];
  float acc0 = live ? x[(size_t)node * 7 + f] * dn * dn : 0.0f;
  float acc1 = 0.0f;
  int beg = rowptr[node], end = rowptr[node + 1];
  int i = beg;
  for (; i + 1 < end; i += 2) {
    int s0 = csr_src[i];
    int s1 = csr_src[i + 1];
    float w0 = dinv[s0] * dn;
    float w1 = dinv[s1] * dn;
    if (live) {
      acc0 = fmaf(x[(size_t)s0 * 7 + f], w0, acc0);
      acc1 = fmaf(x[(size_t)s1 * 7 + f], w1, acc1);
    }
  }
  if (i < end && live) {
    int s = csr_src[i];
    acc0 = fmaf(x[(size_t)s * 7 + f], dinv[s] * dn, acc0);
  }
  aggx[(size_t)node * 8 + f] = acc0 + acc1;
}

// g1 = dinv[n] * ( h1s[n] + sum_{s in N(n)} h1s[s] ); 4 edges/wave, bf16 rows
__global__ __launch_bounds__(256)
void gather4_kernel(const int* __restrict__ rowptr, const int* __restrict__ csr_src,
                    const float* __restrict__ dinv, const uint4* __restrict__ h1s,
                    uint4* __restrict__ g1, int n_nodes) {
  int wid = (blockIdx.x * TPB + threadIdx.x) >> 6;
  if (wid >= n_nodes) return;
  int lane = threadIdx.x & 63;
  int qtr = lane >> 4;
  int l = lane & 15;
  float acc[8];
  #pragma unroll
  for (int j = 0; j < 8; ++j) acc[j] = 0.0f;
  auto addv = [&](uint4 v) {
    unsigned int u[4] = {v.x, v.y, v.z, v.w};
    #pragma unroll
    for (int p = 0; p < 4; ++p) {
      acc[2 * p]     += __uint_as_float(u[p] << 16);
      acc[2 * p + 1] += __uint_as_float(u[p] & 0xffff0000u);
    }
  };
  if (qtr == 0) addv(h1s[(size_t)wid * 16 + l]);  // self term
  int beg = rowptr[wid], end = rowptr[wid + 1];
  int i = beg + qtr;
  for (; i + 4 < end; i += 8) {
    int s0 = csr_src[i];
    int s1 = csr_src[i + 4];
    uint4 v0 = h1s[(size_t)s0 * 16 + l];
    uint4 v1 = h1s[(size_t)s1 * 16 + l];
    addv(v0);
    addv(v1);
  }
  if (i < end) addv(h1s[(size_t)csr_src[i] * 16 + l]);
  #pragma unroll
  for (int j = 0; j < 8; ++j) {
    acc[j] += __shfl_xor(acc[j], 16, 64);
    acc[j] += __shfl_xor(acc[j], 32, 64);
  }
  if (qtr == 0) {
    float dn = dinv[wid];
    unsigned int w[4];
    #pragma unroll
    for (int p = 0; p < 4; ++p) {
      unsigned int lo = (unsigned int)(unsigned short)f2bf(acc[2 * p] * dn);
      unsigned int hi = (unsigned int)(unsigned short)f2bf(acc[2 * p + 1] * dn);
      w[p] = lo | (hi << 16);
    }
    uint4 o; o.x = w[0]; o.y = w[1]; o.z = w[2]; o.w = w[3];
    g1[(size_t)wid * 16 + l] = o;
  }
}

// Register-tiled SGEMM (layer-1 only: K=8); bf16 out, scale[row] after relu
template<int K, int CO>
__global__ __launch_bounds__(256)
void mm_tiled(const float* __restrict__ in, const float* __restrict__ W,
              const float* __restrict__ bias, const float* __restrict__ scale,
              unsigned short* __restrict__ outv, int n_rows) {
  constexpr int BM = 64;
  constexpr int BK = K;
  constexpr int SS = BK + 1 + (BK & 1);
  constexpr int TM = 4;
  constexpr int TN = CO / 16;
  __shared__ float s_in[BM][SS];
  __shared__ float s_w[BK][CO];
  const int tid = threadIdx.x;
  const int base = blockIdx.x * BM;
  const int tr = tid >> 4;
  const int tc = tid & 15;

  float acc[TM][TN];
  #pragma unroll
  for (int m = 0; m < TM; ++m)
    #pragma unroll
    for (int n = 0; n < TN; ++n) acc[m][n] = 0.0f;

  {
    constexpr int F4 = BM * (BK / 4);
    #pragma unroll
    for (int t = tid; t < F4; t += TPB) {
      int r = t / (BK / 4), c4 = t % (BK / 4);
      int row = base + r;
      float4 v = make_float4(0.f, 0.f, 0.f, 0.f);
      if (row < n_rows) v = *(const float4*)(in + (size_t)row * K + c4 * 4);
      s_in[r][c4 * 4 + 0] = v.x;
      s_in[r][c4 * 4 + 1] = v.y;
      s_in[r][c4 * 4 + 2] = v.z;
      s_in[r][c4 * 4 + 3] = v.w;
    }
    constexpr int WF4 = BK * CO / 4;
    #pragma unroll
    for (int t = tid; t < WF4; t += TPB)
      *(float4*)(&s_w[0][0] + t * 4) = *(const float4*)(W + t * 4);
  }
  __syncthreads();

  #pragma unroll
  for (int kk = 0; kk < BK; ++kk) {
    float a[TM], b[TN];
    #pragma unroll
    for (int m = 0; m < TM; ++m) a[m] = s_in[tr * TM + m][kk];
    #pragma unroll
    for (int n = 0; n < TN; ++n) b[n] = s_w[kk][tc + 16 * n];
    #pragma unroll
    for (int m = 0; m < TM; ++m)
      #pragma unroll
      for (int n = 0; n < TN; ++n) acc[m][n] = fmaf(a[m], b[n], acc[m][n]);
  }

  #pragma unroll
  for (int m = 0; m < TM; ++m) {
    int row = base + tr * TM + m;
    if (row < n_rows) {
      float sc = scale[row];
      #pragma unroll
      for (int n = 0; n < TN; ++n) {
        int j = tc + 16 * n;
        float v = fmaxf(acc[m][n] + bias[j], 0.0f) * sc;
        outv[(size_t)row * CO + j] = (unsigned short)f2bf(v);
      }
    }
  }
}

// MFMA GEMM: out(bf16)[n_rows,N] = A(bf16)[n_rows,K] @ WT(bf16)[N,K]^T (+bias)(+relu)
template<int K, int N>
__global__ __launch_bounds__(256)
void mm_mfma(const unsigned short* __restrict__ A, const unsigned short* __restrict__ WT,
             const float* __restrict__ bias, unsigned short* __restrict__ out,
             int n_rows, int do_relu) {
  constexpr int KS = K / 32;
  constexpr int NT = N / 16;
  const int lane = threadIdx.x & 63;
  const int col = lane & 15;
  const int sub = lane >> 4;
  const int wid = threadIdx.x >> 6;

  bf16x8 bfrag[KS][NT];
  #pragma unroll
  for (int ks = 0; ks < KS; ++ks)
    #pragma unroll
    for (int nt = 0; nt < NT; ++nt)
      bfrag[ks][nt] = *(const bf16x8*)(WT + (size_t)(nt * 16 + col) * K + ks * 32 + sub * 8);
  float bv[NT];
  #pragma unroll
  for (int nt = 0; nt < NT; ++nt) bv[nt] = bias ? bias[nt * 16 + col] : 0.0f;

  int ntiles = (n_rows + 15) >> 4;
  int stride = gridDim.x * 4;
  for (int tile = blockIdx.x * 4 + wid; tile < ntiles; tile += stride) {
    int row_a = tile * 16 + col;
    if (row_a >= n_rows) row_a = n_rows - 1;
    bf16x8 afrag[KS];
    #pragma unroll
    for (int ks = 0; ks < KS; ++ks)
      afrag[ks] = *(const bf16x8*)(A + (size_t)row_a * K + ks * 32 + sub * 8);
    f32x4 acc[NT];
    #pragma unroll
    for (int nt = 0; nt < NT; ++nt) acc[nt] = {0.f, 0.f, 0.f, 0.f};
    #pragma unroll
    for (int ks = 0; ks < KS; ++ks)
      #pragma unroll
      for (int nt = 0; nt < NT; ++nt)
        acc[nt] = __builtin_amdgcn_mfma_f32_16x16x32_bf16(afrag[ks], bfrag[ks][nt], acc[nt], 0, 0, 0);
    #pragma unroll
    for (int r = 0; r < 4; ++r) {
      int ro = tile * 16 + sub * 4 + r;
      if (ro < n_rows) {
        #pragma unroll
        for (int nt = 0; nt < NT; ++nt) {
          float v = acc[nt][r] + bv[nt];
          if (do_relu) v = fmaxf(v, 0.0f);
          out[(size_t)ro * N + nt * 16 + col] = (unsigned short)f2bf(v);
        }
      }
    }
  }
}

// Dual MFMA GEMM: atab = A@WcaT^T + bca ; btab = A@WcbT^T + bcb.
// afrag loaded once per tile; B-frags streamed (32KB tables, L2/L1-hot).
__global__ __launch_bounds__(256)
void mm_mfma_dual_kernel(const unsigned short* __restrict__ A,
                         const unsigned short* __restrict__ WTa,
                         const unsigned short* __restrict__ WTb,
                         const float* __restrict__ ba, const float* __restrict__ bb,
                         unsigned short* __restrict__ outa, unsigned short* __restrict__ outb,
                         int n_rows) {
  const int lane = threadIdx.x & 63;
  const int col = lane & 15;
  const int sub = lane >> 4;
  const int wid = threadIdx.x >> 6;
  float bva[8], bvb[8];
  #pragma unroll
  for (int nt = 0; nt < 8; ++nt) {
    bva[nt] = ba[nt * 16 + col];
    bvb[nt] = bb[nt * 16 + col];
  }
  int ntiles = (n_rows + 15) >> 4;
  int stride = gridDim.x * 4;
  for (int tile = blockIdx.x * 4 + wid; tile < ntiles; tile += stride) {
    int row_a = tile * 16 + col;
    if (row_a >= n_rows) row_a = n_rows - 1;
    bf16x8 afrag[4];
    #pragma unroll
    for (int ks = 0; ks < 4; ++ks)
      afrag[ks] = *(const bf16x8*)(A + (size_t)row_a * 128 + ks * 32 + sub * 8);
    // set A
    f32x4 acc[8];
    #pragma unroll
    for (int nt = 0; nt < 8; ++nt) acc[nt] = {0.f, 0.f, 0.f, 0.f};
    #pragma unroll
    for (int ks = 0; ks < 4; ++ks)
      #pragma unroll
      for (int nt = 0; nt < 8; ++nt) {
        bf16x8 bfrag = *(const bf16x8*)(WTa + (size_t)(nt * 16 + col) * 128 + ks * 32 + sub * 8);
        acc[nt] = __builtin_amdgcn_mfma_f32_16x16x32_bf16(afrag[ks], bfrag, acc[nt], 0, 0, 0);
      }
    #pragma unroll
    for (int r = 0; r < 4; ++r) {
      int ro = tile * 16 + sub * 4 + r;
      if (ro < n_rows)
        #pragma unroll
        for (int nt = 0; nt < 8; ++nt)
          outa[(size_t)ro * 128 + nt * 16 + col] = (unsigned short)f2bf(acc[nt][r] + bva[nt]);
    }
    // set B
    #pragma unroll
    for (int nt = 0; nt < 8; ++nt) acc[nt] = {0.f, 0.f, 0.f, 0.f};
    #pragma unroll
    for (int ks = 0; ks < 4; ++ks)
      #pragma unroll
      for (int nt = 0; nt < 8; ++nt) {
        bf16x8 bfrag = *(const bf16x8*)(WTb + (size_t)(nt * 16 + col) * 128 + ks * 32 + sub * 8);
        acc[nt] = __builtin_amdgcn_mfma_f32_16x16x32_bf16(afrag[ks], bfrag, acc[nt], 0, 0, 0);
      }
    #pragma unroll
    for (int r = 0; r < 4; ++r) {
      int ro = tile * 16 + sub * 4 + r;
      if (ro < n_rows)
        #pragma unroll
        for (int nt = 0; nt < 8; ++nt)
          outb[(size_t)ro * 128 + nt * 16 + col] = (unsigned short)f2bf(acc[nt][r] + bvb[nt]);
    }
  }
}

// MFMA decoder: 16 queries per wave-tile. (layouts validated)
__global__ __launch_bounds__(256)
void decoder_mfma_kernel(const int* __restrict__ qsrc, const int* __restrict__ qdst,
                         const unsigned short* __restrict__ atab,
                         const unsigned short* __restrict__ btab,
                         const float* __restrict__ Wd2, const float* __restrict__ bd2,
                         const float* __restrict__ Wd3, const float* __restrict__ bd3,
                         float* __restrict__ out, int n_query) {
  const int lane = threadIdx.x & 63;
  const int col = lane & 15;
  const int sub = lane >> 4;

  bf16x8 bfrag[4][4];
  #pragma unroll
  for (int ks = 0; ks < 4; ++ks)
    #pragma unroll
    for (int nt = 0; nt < 4; ++nt) {
      bf16x8 f;
      #pragma unroll
      for (int j = 0; j < 8; ++j) {
        int k = ks * 32 + sub * 8 + j;
        int n = nt * 16 + col;
        f[j] = f2bf(Wd2[k * 64 + n]);
      }
      bfrag[ks][nt] = f;
    }
  float bd2v[4], wd3v[4];
  #pragma unroll
  for (int nt = 0; nt < 4; ++nt) {
    bd2v[nt] = bd2[nt * 16 + col];
    wd3v[nt] = Wd3[nt * 16 + col];
  }
  const float bd3s = bd3[0];

  int wave = (blockIdx.x * TPB + threadIdx.x) >> 6;
  int nwaves = gridDim.x * (TPB / 64);
  int ntiles = (n_query + 15) >> 4;
  for (int t = wave; t < ntiles; t += nwaves) {
    int qb = t << 4;
    int q = qb + col;
    if (q >= n_query) q = n_query - 1;
    int si = qsrc[q], di = qdst[q];
    const bf16x8* ar = (const bf16x8*)(atab + (size_t)si * 128);
    const bf16x8* br = (const bf16x8*)(btab + (size_t)di * 128);
    bf16x8 afrag[4];
    #pragma unroll
    for (int ks = 0; ks < 4; ++ks) {
      bf16x8 av = ar[ks * 4 + sub];
      bf16x8 bv = br[ks * 4 + sub];
      bf16x8 d;
      #pragma unroll
      for (int j = 0; j < 8; ++j)
        d[j] = f2bf(fmaxf(bf2f(av[j]) + bf2f(bv[j]), 0.0f));  // d1 = relu(a+b)
      afrag[ks] = d;
    }
    f32x4 acc[4];
    #pragma unroll
    for (int nt = 0; nt < 4; ++nt) acc[nt] = {0.f, 0.f, 0.f, 0.f};
    #pragma unroll
    for (int ks = 0; ks < 4; ++ks)
      #pragma unroll
      for (int nt = 0; nt < 4; ++nt)
        acc[nt] = __builtin_amdgcn_mfma_f32_16x16x32_bf16(afrag[ks], bfrag[ks][nt], acc[nt], 0, 0, 0);
    float part[4] = {0.f, 0.f, 0.f, 0.f};
    #pragma unroll
    for (int nt = 0; nt < 4; ++nt)
      #pragma unroll
      for (int r = 0; r < 4; ++r) {
        float v = fmaxf(acc[nt][r] + bd2v[nt], 0.0f);
        part[r] = fmaf(v, wd3v[nt], part[r]);
      }
    #pragma unroll
    for (int off = 1; off < 16; off <<= 1)
      #pragma unroll
      for (int r = 0; r < 4; ++r) part[r] += __shfl_xor(part[r], off, 64);
    if (col == 0) {
      int row0 = qb + sub * 4;
      #pragma unroll
      for (int r = 0; r < 4; ++r) {
        int qq = row0 + r;
        if (qq < n_query) out[qq] = 1.0f / (1.0f + __expf(-(part[r] + bd3s)));
      }
    }
  }
}

extern "C" void kernel_launch(void* const* d_in, const int* in_sizes, int n_in,
                              void* d_out, int out_size, void* d_ws, size_t ws_size,
                              hipStream_t stream) {
  const float* x    = (const float*)d_in[0];
  const int*   ei   = (const int*)d_in[1];
  const int*   qe   = (const int*)d_in[2];
  const float* W1   = (const float*)d_in[3];
  const float* b1   = (const float*)d_in[4];
  const float* W2   = (const float*)d_in[5];
  const float* b2   = (const float*)d_in[6];
  const float* Wfc  = (const float*)d_in[7];
  const float* bfc  = (const float*)d_in[8];
  const float* Wd1  = (const float*)d_in[9];
  const float* bd1  = (const float*)d_in[10];
  const float* Wd2  = (const float*)d_in[11];
  const float* bd2  = (const float*)d_in[12];
  const float* Wd3  = (const float*)d_in[13];
  const float* bd3  = (const float*)d_in[14];
  float* out = (float*)d_out;

  const int n_nodes = in_sizes[0] / 7;
  const int n_edges = in_sizes[1] / 2;
  const int n_query = in_sizes[2] / 2;
  const int* e_src = ei;
  const int* e_dst = ei + n_edges;
  const int* q_src = qe;
  const int* q_dst = qe + n_query;

  const int n_blk1 = cdiv(n_edges, EPB);
  const int bh_len = NB * n_blk1;
  const int n_bucket = cdiv(n_nodes, NPB);

  // ---- workspace layout ----
  char* wp = (char*)d_ws;
  auto take = [&](size_t bytes) { char* p = wp; wp += (bytes + 255) & ~size_t(255); return p; };
  float* dinv    = (float*)take((size_t)n_nodes * 4);
  int*   counts  = (int*)  take((size_t)n_nodes * 4);
  int*   rowptr  = (int*)  take((size_t)(n_nodes + 1) * 4);
  int*   bsum    = (int*)  take(512 * 4);
  int*   bh      = (int*)  take((size_t)(bh_len + 1) * 4);
  int*   eoff    = (int*)  take((size_t)(bh_len + 1) * 4);
  unsigned int* ebuf = (unsigned int*)take((size_t)n_edges * 4);
  int*   csr_src = (int*)  take((size_t)n_edges * 4);
  float* aggx    = (float*)take((size_t)n_nodes * 8 * 4);
  float* W1p     = (float*)take(8 * 128 * 4);
  unsigned short* W2T   = (unsigned short*)take(128 * 128 * 2);
  unsigned short* WcaT  = (unsigned short*)take(128 * 128 * 2);
  unsigned short* WcbT  = (unsigned short*)take(128 * 128 * 2);
  float* bca     = (float*)take(128 * 4);
  float* bcb     = (float*)take(128 * 4);
  float* bufP    = (float*)take((size_t)n_nodes * 128 * 4);
  float* bufQ    = (float*)take((size_t)n_nodes * 128 * 4);
  float* bufR    = (float*)take((size_t)n_nodes * 64 * 4);

  const int mm_blocks = cdiv(n_nodes, 64);
  const int node_blocks = cdiv(n_nodes, TPB);
  const int scan_blocks = cdiv(n_nodes, SCAN_B);
  const int escan_blocks = cdiv(bh_len, SCAN_B);
  const int mfma_blocks = min(1024, cdiv(cdiv(n_nodes, 16), 4));

  // ---- CSR build (no global atomics): 8 dispatches ----
  bucket_hist_kernel<<<n_blk1, TPB, 0, stream>>>(e_dst, bh, n_edges, n_blk1);
  scan_block_kernel<<<escan_blocks, SCAN_B, 0, stream>>>(bh, eoff, bsum, bh_len);
  scan_fin_kernel<<<cdiv(bh_len, TPB), TPB, 0, stream>>>(eoff, bsum, escan_blocks, bh_len, n_edges);
  bucket_scatter_kernel<<<n_blk1, TPB, 0, stream>>>(e_src, e_dst, eoff, ebuf, n_edges, n_blk1);
  node_hist_kernel<<<n_bucket, TPB, 0, stream>>>(ebuf, eoff, counts, dinv, n_blk1, n_nodes);
  scan_block_kernel<<<scan_blocks, SCAN_B, 0, stream>>>(counts, rowptr, bsum, n_nodes);
  scan_fin_kernel<<<node_blocks, TPB, 0, stream>>>(rowptr, bsum, scan_blocks, n_nodes, n_edges);
  final_scatter_kernel<<<n_bucket, TPB, 0, stream>>>(ebuf, eoff, rowptr, csr_src, n_blk1, n_nodes);

  // ---- prep ----
  prep_weights_kernel<<<129, TPB, 0, stream>>>(W1, W2, Wfc, bfc, Wd1, bd1,
                                               W1p, W2T, WcaT, WcbT, bca, bcb);

  // ---- layer 1: aggx = A_hat x ; h1s(bf16) = relu(aggx @ W1p + b1) * dinv ----
  agg_x_kernel<<<cdiv(n_nodes * 8, TPB), TPB, 0, stream>>>(rowptr, csr_src, dinv, x, aggx, n_nodes);
  mm_tiled<8, 128><<<mm_blocks, TPB, 0, stream>>>(aggx, W1p, b1, dinv, (unsigned short*)bufP, n_nodes);
  // bufP = h1s (bf16, prescaled)

  // ---- layer 2 (split, R10 structure): g1 -> h2 ----
  gather4_kernel<<<cdiv(n_nodes * 64, TPB), TPB, 0, stream>>>(rowptr, csr_src, dinv,
                                                              (const uint4*)bufP, (uint4*)bufQ, n_nodes);
  mm_mfma<128, 128><<<mfma_blocks, TPB, 0, stream>>>((const unsigned short*)bufQ, W2T, b2,
                                                     (unsigned short*)bufR, n_nodes, 1);
  // bufR = h2 (bf16, n*128 shorts = n*64 floats: exact fit)

  // ---- decoder tables (fc folded, dual): atab = h2@Wca + bca ; btab = h2@Wcb + bcb ----
  unsigned short* atab = (unsigned short*)bufP;
  unsigned short* btab = (unsigned short*)bufQ;
  mm_mfma_dual_kernel<<<mfma_blocks, TPB, 0, stream>>>((const unsigned short*)bufR, WcaT, WcbT,
                                                       bca, bcb, atab, btab, n_nodes);

  // ---- per-query decode (MFMA) ----
  decoder_mfma_kernel<<<2048, TPB, 0, stream>>>(q_src, q_dst, atab, btab, Wd2, bd2, Wd3, bd3, out, n_query);
}

// Round 13
// 302.665 us; speedup vs baseline: 1.2246x; 1.0080x over previous
//
#include <hip/hip_runtime.h>
#include <hip/hip_bf16.h>
#include <cstdint>
#include <cstddef>

constexpr int TPB = 256;
constexpr int SCAN_B = 1024;
constexpr int NB   = 128;      // buckets for CSR build
constexpr int BSH  = 10;       // nodes per bucket = 1024
constexpr int NPB  = 1 << BSH;
constexpr int EPB  = 4096;     // edges per block in bucket passes
using bf16x8 = __attribute__((ext_vector_type(8))) short;
using f32x4  = __attribute__((ext_vector_type(4))) float;

static inline int cdiv(int a, int b) { return (a + b - 1) / b; }

__device__ __forceinline__ float bf2f(short u) {
  return __uint_as_float(((unsigned int)(unsigned short)u) << 16);
}
__device__ __forceinline__ short f2bf(float f) {  // RNE
  unsigned int u = __float_as_uint(f);
  return (short)((u + 0x7FFF + ((u >> 16) & 1)) >> 16);
}

// ---------- CSR build: zero global atomics ----------

__global__ __launch_bounds__(256)
void bucket_hist_kernel(const int* __restrict__ dst, int* __restrict__ bh,
                        int e_cnt, int n_blk) {
  __shared__ int h[NB];
  int tid = threadIdx.x;
  if (tid < NB) h[tid] = 0;
  __syncthreads();
  int base = blockIdx.x * EPB;
  for (int i = tid; i < EPB; i += TPB) {
    int e = base + i;
    if (e < e_cnt) atomicAdd(&h[dst[e] >> BSH], 1);
  }
  __syncthreads();
  if (tid < NB) bh[tid * n_blk + blockIdx.x] = h[tid];
}

__global__ __launch_bounds__(SCAN_B)
void scan_block_kernel(const int* __restrict__ counts, int* __restrict__ rowptr,
                       int* __restrict__ bsum, int n) {
  __shared__ int wsum[16];
  const int tid = threadIdx.x;
  const int i = blockIdx.x * SCAN_B + tid;
  const int lane = tid & 63;
  const int w = tid >> 6;
  int v = (i < n) ? counts[i] : 0;
  int s = v;
  #pragma unroll
  for (int off = 1; off < 64; off <<= 1) {
    int t = __shfl_up(s, off, 64);
    if (lane >= off) s += t;
  }
  if (lane == 63) wsum[w] = s;
  __syncthreads();
  if (tid < 16) {
    int ws_ = wsum[tid];
    #pragma unroll
    for (int off = 1; off < 16; off <<= 1) {
      int t = __shfl_up(ws_, off, 64);
      if (tid >= off) ws_ += t;
    }
    wsum[tid] = ws_;
  }
  __syncthreads();
  int woff = (w == 0) ? 0 : wsum[w - 1];
  if (i < n) rowptr[i] = woff + s - v;
  if (tid == SCAN_B - 1) bsum[blockIdx.x] = woff + s;
}

// merged carry-scan + offset-add
__global__ __launch_bounds__(256)
void scan_fin_kernel(int* __restrict__ rowptr, const int* __restrict__ bsum,
                     int nb, int n, int total) {
  __shared__ int sb[128];
  int tid = threadIdx.x;
  if (tid == 0) {
    int run = 0;
    for (int b = 0; b < nb; ++b) { sb[b] = run; run += bsum[b]; }
  }
  __syncthreads();
  int i = blockIdx.x * TPB + tid;
  if (i < n) rowptr[i] += sb[i / SCAN_B];
  if (i == 0) rowptr[n] = total;
}

__global__ __launch_bounds__(256)
void bucket_scatter_kernel(const int* __restrict__ src, const int* __restrict__ dst,
                           const int* __restrict__ eoff, unsigned int* __restrict__ ebuf,
                           int e_cnt, int n_blk) {
  __shared__ int cur[NB];
  int tid = threadIdx.x;
  if (tid < NB) cur[tid] = eoff[tid * n_blk + blockIdx.x];
  __syncthreads();
  int base = blockIdx.x * EPB;
  for (int i = tid; i < EPB; i += TPB) {
    int e = base + i;
    if (e < e_cnt) {
      int d = dst[e];
      int b = d >> BSH;
      int pos = atomicAdd(&cur[b], 1);  // LDS atomic
      ebuf[pos] = ((unsigned int)src[e] << BSH) | (unsigned int)(d & (NPB - 1));
    }
  }
}

// per-bucket node hist + dinv, no global atomics
__global__ __launch_bounds__(256)
void node_hist_kernel(const unsigned int* __restrict__ ebuf, const int* __restrict__ eoff,
                      int* __restrict__ counts, float* __restrict__ dinv,
                      int n_blk, int n_nodes) {
  __shared__ int nh[NPB];
  int b = blockIdx.x;
  for (int i = threadIdx.x; i < NPB; i += TPB) nh[i] = 0;
  __syncthreads();
  int wb = eoff[b * n_blk];
  int we = eoff[(b + 1) * n_blk];
  for (int i = wb + threadIdx.x; i < we; i += TPB)
    atomicAdd(&nh[ebuf[i] & (NPB - 1)], 1);  // LDS atomic
  __syncthreads();
  int nbase = b << BSH;
  for (int i = threadIdx.x; i < NPB; i += TPB) {
    int node = nbase + i;
    if (node < n_nodes) {
      counts[node] = nh[i];
      dinv[node] = rsqrtf((float)nh[i] + 1.0f);  // +1 self-loop
    }
  }
}

__global__ __launch_bounds__(256)
void final_scatter_kernel(const unsigned int* __restrict__ ebuf, const int* __restrict__ eoff,
                          const int* __restrict__ rowptr, int* __restrict__ csr_src,
                          int n_blk, int n_nodes) {
  __shared__ int cur[NPB];
  int b = blockIdx.x;
  int nbase = b << BSH;
  for (int i = threadIdx.x; i < NPB; i += TPB) {
    int node = nbase + i;
    cur[i] = (node < n_nodes) ? rowptr[node] : 0;
  }
  __syncthreads();
  int wb = eoff[b * n_blk];
  int we = eoff[(b + 1) * n_blk];
  for (int i = wb + threadIdx.x; i < we; i += TPB) {
    unsigned int p = ebuf[i];
    int pos = atomicAdd(&cur[p & (NPB - 1)], 1);  // LDS atomic
    csr_src[pos] = (int)(p >> BSH);
  }
}

// ---------- prep ----------

// W1p pad + combined biases (block 0), W2T (blocks 1..64),
// combined WcaT/WcbT = (Wfc@Wd1a/b)^T bf16 (blocks 65..128)
__global__ __launch_bounds__(256)
void prep_weights_kernel(const float* __restrict__ W1, const float* __restrict__ W2,
                         const float* __restrict__ Wfc, const float* __restrict__ bfc,
                         const float* __restrict__ Wd1, const float* __restrict__ bd1,
                         float* __restrict__ W1p, unsigned short* __restrict__ W2T,
                         unsigned short* __restrict__ WcaT, unsigned short* __restrict__ WcbT,
                         float* __restrict__ bca, float* __restrict__ bcb) {
  int b = blockIdx.x;
  int tid = threadIdx.x;
  if (b == 0) {
    for (int i = tid; i < 8 * 128; i += TPB)
      W1p[i] = (i < 7 * 128) ? W1[i] : 0.0f;
    int j = tid & 127;
    int which = tid >> 7;
    float acc = which ? 0.0f : bd1[j];
    int mo = which ? 64 : 0;
    #pragma unroll 8
    for (int m = 0; m < 64; ++m) acc = fmaf(bfc[m], Wd1[(mo + m) * 128 + j], acc);
    if (which) bcb[j] = acc; else bca[j] = acc;
  } else if (b <= 64) {
    int idx = (b - 1) * 256 + tid;   // 16384 = W2T elems
    int n = idx >> 7, k = idx & 127;
    W2T[idx] = (unsigned short)f2bf(W2[k * 128 + n]);  // W2T[n][k] = W2[k][n]
  } else {
    int idx = (b - 65) * 256 + tid;  // 16384 combined outputs
    int j = idx >> 7, k = idx & 127;
    float accA = 0.0f, accB = 0.0f;
    #pragma unroll 8
    for (int m = 0; m < 64; ++m) {
      float w = Wfc[k * 64 + m];
      accA = fmaf(w, Wd1[m * 128 + j], accA);
      accB = fmaf(w, Wd1[(64 + m) * 128 + j], accB);
    }
    WcaT[j * 128 + k] = (unsigned short)f2bf(accA);  // [N][K]
    WcbT[j * 128 + k] = (unsigned short)f2bf(accB);
  }
}

// ---------- graph pipeline ----------

// aggx = A_hat @ x (reads x[n,7] directly, feature 7 = 0); 8 lanes/node, 4-chain
__global__ __launch_bounds__(256)
void agg_x_kernel(const int* __restrict__ rowptr, const int* __restrict__ csr_src,
                  const float* __restrict__ dinv, const float* __restrict__ x,
                  float* __restrict__ aggx, int n_nodes) {
  int gid = blockIdx.x * TPB + threadIdx.x;
  int node = gid >> 3;
  int f = gid & 7;
  if (node >= n_nodes) return;
  bool live = (f < 7);
  float dn = dinv[node];
  float acc0 = live ? x[(size_t)node * 7 + f] * dn * dn : 0.0f;
  float acc1 = 0.0f, acc2 = 0.0f, acc3 = 0.0f;
  int beg = rowptr[node], end = rowptr[node + 1];
  int i = beg;
  for (; i + 3 < end; i += 4) {
    int s0 = csr_src[i];
    int s1 = csr_src[i + 1];
    int s2 = csr_src[i + 2];
    int s3 = csr_src[i + 3];
    float w0 = dinv[s0] * dn;
    float w1 = dinv[s1] * dn;
    float w2 = dinv[s2] * dn;
    float w3 = dinv[s3] * dn;
    if (live) {
      acc0 = fmaf(x[(size_t)s0 * 7 + f], w0, acc0);
      acc1 = fmaf(x[(size_t)s1 * 7 + f], w1, acc1);
      acc2 = fmaf(x[(size_t)s2 * 7 + f], w2, acc2);
      acc3 = fmaf(x[(size_t)s3 * 7 + f], w3, acc3);
    }
  }
  for (; i < end; ++i) {
    int s = csr_src[i];
    if (live) acc0 = fmaf(x[(size_t)s * 7 + f], dinv[s] * dn, acc0);
  }
  aggx[(size_t)node * 8 + f] = (acc0 + acc1) + (acc2 + acc3);
}

// g1 = dinv[n] * ( h1s[n] + sum_{s in N(n)} h1s[s] ); 4 edges/wave, 4x unroll
// per quarter => 16 outstanding 256B row-gathers per wave (was 8).
__global__ __launch_bounds__(256)
void gather4_kernel(const int* __restrict__ rowptr, const int* __restrict__ csr_src,
                    const float* __restrict__ dinv, const uint4* __restrict__ h1s,
                    uint4* __restrict__ g1, int n_nodes) {
  int wid = (blockIdx.x * TPB + threadIdx.x) >> 6;
  if (wid >= n_nodes) return;
  int lane = threadIdx.x & 63;
  int qtr = lane >> 4;
  int l = lane & 15;
  float acc[8];
  #pragma unroll
  for (int j = 0; j < 8; ++j) acc[j] = 0.0f;
  auto addv = [&](uint4 v) {
    unsigned int u[4] = {v.x, v.y, v.z, v.w};
    #pragma unroll
    for (int p = 0; p < 4; ++p) {
      acc[2 * p]     += __uint_as_float(u[p] << 16);
      acc[2 * p + 1] += __uint_as_float(u[p] & 0xffff0000u);
    }
  };
  if (qtr == 0) addv(h1s[(size_t)wid * 16 + l]);  // self term
  int beg = rowptr[wid], end = rowptr[wid + 1];
  int i = beg + qtr;
  for (; i + 12 < end; i += 16) {
    int s0 = csr_src[i];
    int s1 = csr_src[i + 4];
    int s2 = csr_src[i + 8];
    int s3 = csr_src[i + 12];
    uint4 v0 = h1s[(size_t)s0 * 16 + l];
    uint4 v1 = h1s[(size_t)s1 * 16 + l];
    uint4 v2 = h1s[(size_t)s2 * 16 + l];
    uint4 v3 = h1s[(size_t)s3 * 16 + l];
    addv(v0);
    addv(v1);
    addv(v2);
    addv(v3);
  }
  for (; i < end; i += 4) addv(h1s[(size_t)csr_src[i] * 16 + l]);
  #pragma unroll
  for (int j = 0; j < 8; ++j) {
    acc[j] += __shfl_xor(acc[j], 16, 64);
    acc[j] += __shfl_xor(acc[j], 32, 64);
  }
  if (qtr == 0) {
    float dn = dinv[wid];
    unsigned int w[4];
    #pragma unroll
    for (int p = 0; p < 4; ++p) {
      unsigned int lo = (unsigned int)(unsigned short)f2bf(acc[2 * p] * dn);
      unsigned int hi = (unsigned int)(unsigned short)f2bf(acc[2 * p + 1] * dn);
      w[p] = lo | (hi << 16);
    }
    uint4 o; o.x = w[0]; o.y = w[1]; o.z = w[2]; o.w = w[3];
    g1[(size_t)wid * 16 + l] = o;
  }
}

// Register-tiled SGEMM (layer-1 only: K=8); bf16 out, scale[row] after relu
template<int K, int CO>
__global__ __launch_bounds__(256)
void mm_tiled(const float* __restrict__ in, const float* __restrict__ W,
              const float* __restrict__ bias, const float* __restrict__ scale,
              unsigned short* __restrict__ outv, int n_rows) {
  constexpr int BM = 64;
  constexpr int BK = K;
  constexpr int SS = BK + 1 + (BK & 1);
  constexpr int TM = 4;
  constexpr int TN = CO / 16;
  __shared__ float s_in[BM][SS];
  __shared__ float s_w[BK][CO];
  const int tid = threadIdx.x;
  const int base = blockIdx.x * BM;
  const int tr = tid >> 4;
  const int tc = tid & 15;

  float acc[TM][TN];
  #pragma unroll
  for (int m = 0; m < TM; ++m)
    #pragma unroll
    for (int n = 0; n < TN; ++n) acc[m][n] = 0.0f;

  {
    constexpr int F4 = BM * (BK / 4);
    #pragma unroll
    for (int t = tid; t < F4; t += TPB) {
      int r = t / (BK / 4), c4 = t % (BK / 4);
      int row = base + r;
      float4 v = make_float4(0.f, 0.f, 0.f, 0.f);
      if (row < n_rows) v = *(const float4*)(in + (size_t)row * K + c4 * 4);
      s_in[r][c4 * 4 + 0] = v.x;
      s_in[r][c4 * 4 + 1] = v.y;
      s_in[r][c4 * 4 + 2] = v.z;
      s_in[r][c4 * 4 + 3] = v.w;
    }
    constexpr int WF4 = BK * CO / 4;
    #pragma unroll
    for (int t = tid; t < WF4; t += TPB)
      *(float4*)(&s_w[0][0] + t * 4) = *(const float4*)(W + t * 4);
  }
  __syncthreads();

  #pragma unroll
  for (int kk = 0; kk < BK; ++kk) {
    float a[TM], b[TN];
    #pragma unroll
    for (int m = 0; m < TM; ++m) a[m] = s_in[tr * TM + m][kk];
    #pragma unroll
    for (int n = 0; n < TN; ++n) b[n] = s_w[kk][tc + 16 * n];
    #pragma unroll
    for (int m = 0; m < TM; ++m)
      #pragma unroll
      for (int n = 0; n < TN; ++n) acc[m][n] = fmaf(a[m], b[n], acc[m][n]);
  }

  #pragma unroll
  for (int m = 0; m < TM; ++m) {
    int row = base + tr * TM + m;
    if (row < n_rows) {
      float sc = scale[row];
      #pragma unroll
      for (int n = 0; n < TN; ++n) {
        int j = tc + 16 * n;
        float v = fmaxf(acc[m][n] + bias[j], 0.0f) * sc;
        outv[(size_t)row * CO + j] = (unsigned short)f2bf(v);
      }
    }
  }
}

// MFMA GEMM: out(bf16)[n_rows,N] = A(bf16)[n_rows,K] @ WT(bf16)[N,K]^T (+bias)(+relu)
template<int K, int N>
__global__ __launch_bounds__(256)
void mm_mfma(const unsigned short* __restrict__ A, const unsigned short* __restrict__ WT,
             const float* __restrict__ bias, unsigned short* __restrict__ out,
             int n_rows, int do_relu) {
  constexpr int KS = K / 32;
  constexpr int NT = N / 16;
  const int lane = threadIdx.x & 63;
  const int col = lane & 15;
  const int sub = lane >> 4;
  const int wid = threadIdx.x >> 6;

  bf16x8 bfrag[KS][NT];
  #pragma unroll
  for (int ks = 0; ks < KS; ++ks)
    #pragma unroll
    for (int nt = 0; nt < NT; ++nt)
      bfrag[ks][nt] = *(const bf16x8*)(WT + (size_t)(nt * 16 + col) * K + ks * 32 + sub * 8);
  float bv[NT];
  #pragma unroll
  for (int nt = 0; nt < NT; ++nt) bv[nt] = bias ? bias[nt * 16 + col] : 0.0f;

  int ntiles = (n_rows + 15) >> 4;
  int stride = gridDim.x * 4;
  for (int tile = blockIdx.x * 4 + wid; tile < ntiles; tile += stride) {
    int row_a = tile * 16 + col;
    if (row_a >= n_rows) row_a = n_rows - 1;
    bf16x8 afrag[KS];
    #pragma unroll
    for (int ks = 0; ks < KS; ++ks)
      afrag[ks] = *(const bf16x8*)(A + (size_t)row_a * K + ks * 32 + sub * 8);
    f32x4 acc[NT];
    #pragma unroll
    for (int nt = 0; nt < NT; ++nt) acc[nt] = {0.f, 0.f, 0.f, 0.f};
    #pragma unroll
    for (int ks = 0; ks < KS; ++ks)
      #pragma unroll
      for (int nt = 0; nt < NT; ++nt)
        acc[nt] = __builtin_amdgcn_mfma_f32_16x16x32_bf16(afrag[ks], bfrag[ks][nt], acc[nt], 0, 0, 0);
    #pragma unroll
    for (int r = 0; r < 4; ++r) {
      int ro = tile * 16 + sub * 4 + r;
      if (ro < n_rows) {
        #pragma unroll
        for (int nt = 0; nt < NT; ++nt) {
          float v = acc[nt][r] + bv[nt];
          if (do_relu) v = fmaxf(v, 0.0f);
          out[(size_t)ro * N + nt * 16 + col] = (unsigned short)f2bf(v);
        }
      }
    }
  }
}

// Dual MFMA GEMM: atab = A@WcaT^T + bca ; btab = A@WcbT^T + bcb.
__global__ __launch_bounds__(256)
void mm_mfma_dual_kernel(const unsigned short* __restrict__ A,
                         const unsigned short* __restrict__ WTa,
                         const unsigned short* __restrict__ WTb,
                         const float* __restrict__ ba, const float* __restrict__ bb,
                         unsigned short* __restrict__ outa, unsigned short* __restrict__ outb,
                         int n_rows) {
  const int lane = threadIdx.x & 63;
  const int col = lane & 15;
  const int sub = lane >> 4;
  const int wid = threadIdx.x >> 6;
  float bva[8], bvb[8];
  #pragma unroll
  for (int nt = 0; nt < 8; ++nt) {
    bva[nt] = ba[nt * 16 + col];
    bvb[nt] = bb[nt * 16 + col];
  }
  int ntiles = (n_rows + 15) >> 4;
  int stride = gridDim.x * 4;
  for (int tile = blockIdx.x * 4 + wid; tile < ntiles; tile += stride) {
    int row_a = tile * 16 + col;
    if (row_a >= n_rows) row_a = n_rows - 1;
    bf16x8 afrag[4];
    #pragma unroll
    for (int ks = 0; ks < 4; ++ks)
      afrag[ks] = *(const bf16x8*)(A + (size_t)row_a * 128 + ks * 32 + sub * 8);
    // set A
    f32x4 acc[8];
    #pragma unroll
    for (int nt = 0; nt < 8; ++nt) acc[nt] = {0.f, 0.f, 0.f, 0.f};
    #pragma unroll
    for (int ks = 0; ks < 4; ++ks)
      #pragma unroll
      for (int nt = 0; nt < 8; ++nt) {
        bf16x8 bfrag = *(const bf16x8*)(WTa + (size_t)(nt * 16 + col) * 128 + ks * 32 + sub * 8);
        acc[nt] = __builtin_amdgcn_mfma_f32_16x16x32_bf16(afrag[ks], bfrag, acc[nt], 0, 0, 0);
      }
    #pragma unroll
    for (int r = 0; r < 4; ++r) {
      int ro = tile * 16 + sub * 4 + r;
      if (ro < n_rows)
        #pragma unroll
        for (int nt = 0; nt < 8; ++nt)
          outa[(size_t)ro * 128 + nt * 16 + col] = (unsigned short)f2bf(acc[nt][r] + bva[nt]);
    }
    // set B
    #pragma unroll
    for (int nt = 0; nt < 8; ++nt) acc[nt] = {0.f, 0.f, 0.f, 0.f};
    #pragma unroll
    for (int ks = 0; ks < 4; ++ks)
      #pragma unroll
      for (int nt = 0; nt < 8; ++nt) {
        bf16x8 bfrag = *(const bf16x8*)(WTb + (size_t)(nt * 16 + col) * 128 + ks * 32 + sub * 8);
        acc[nt] = __builtin_amdgcn_mfma_f32_16x16x32_bf16(afrag[ks], bfrag, acc[nt], 0, 0, 0);
      }
    #pragma unroll
    for (int r = 0; r < 4; ++r) {
      int ro = tile * 16 + sub * 4 + r;
      if (ro < n_rows)
        #pragma unroll
        for (int nt = 0; nt < 8; ++nt)
          outb[(size_t)ro * 128 + nt * 16 + col] = (unsigned short)f2bf(acc[nt][r] + bvb[nt]);
    }
  }
}

// MFMA decoder: 16 queries per wave-tile. (layouts validated)
__global__ __launch_bounds__(256)
void decoder_mfma_kernel(const int* __restrict__ qsrc, const int* __restrict__ qdst,
                         const unsigned short* __restrict__ atab,
                         const unsigned short* __restrict__ btab,
                         const float* __restrict__ Wd2, const float* __restrict__ bd2,
                         const float* __restrict__ Wd3, const float* __restrict__ bd3,
                         float* __restrict__ out, int n_query) {
  const int lane = threadIdx.x & 63;
  const int col = lane & 15;
  const int sub = lane >> 4;

  bf16x8 bfrag[4][4];
  #pragma unroll
  for (int ks = 0; ks < 4; ++ks)
    #pragma unroll
    for (int nt = 0; nt < 4; ++nt) {
      bf16x8 f;
      #pragma unroll
      for (int j = 0; j < 8; ++j) {
        int k = ks * 32 + sub * 8 + j;
        int n = nt * 16 + col;
        f[j] = f2bf(Wd2[k * 64 + n]);
      }
      bfrag[ks][nt] = f;
    }
  float bd2v[4], wd3v[4];
  #pragma unroll
  for (int nt = 0; nt < 4; ++nt) {
    bd2v[nt] = bd2[nt * 16 + col];
    wd3v[nt] = Wd3[nt * 16 + col];
  }
  const float bd3s = bd3[0];

  int wave = (blockIdx.x * TPB + threadIdx.x) >> 6;
  int nwaves = gridDim.x * (TPB / 64);
  int ntiles = (n_query + 15) >> 4;
  for (int t = wave; t < ntiles; t += nwaves) {
    int qb = t << 4;
    int q = qb + col;
    if (q >= n_query) q = n_query - 1;
    int si = qsrc[q], di = qdst[q];
    const bf16x8* ar = (const bf16x8*)(atab + (size_t)si * 128);
    const bf16x8* br = (const bf16x8*)(btab + (size_t)di * 128);
    bf16x8 afrag[4];
    #pragma unroll
    for (int ks = 0; ks < 4; ++ks) {
      bf16x8 av = ar[ks * 4 + sub];
      bf16x8 bv = br[ks * 4 + sub];
      bf16x8 d;
      #pragma unroll
      for (int j = 0; j < 8; ++j)
        d[j] = f2bf(fmaxf(bf2f(av[j]) + bf2f(bv[j]), 0.0f));  // d1 = relu(a+b)
      afrag[ks] = d;
    }
    f32x4 acc[4];
    #pragma unroll
    for (int nt = 0; nt < 4; ++nt) acc[nt] = {0.f, 0.f, 0.f, 0.f};
    #pragma unroll
    for (int ks = 0; ks < 4; ++ks)
      #pragma unroll
      for (int nt = 0; nt < 4; ++nt)
        acc[nt] = __builtin_amdgcn_mfma_f32_16x16x32_bf16(afrag[ks], bfrag[ks][nt], acc[nt], 0, 0, 0);
    float part[4] = {0.f, 0.f, 0.f, 0.f};
    #pragma unroll
    for (int nt = 0; nt < 4; ++nt)
      #pragma unroll
      for (int r = 0; r < 4; ++r) {
        float v = fmaxf(acc[nt][r] + bd2v[nt], 0.0f);
        part[r] = fmaf(v, wd3v[nt], part[r]);
      }
    #pragma unroll
    for (int off = 1; off < 16; off <<= 1)
      #pragma unroll
      for (int r = 0; r < 4; ++r) part[r] += __shfl_xor(part[r], off, 64);
    if (col == 0) {
      int row0 = qb + sub * 4;
      #pragma unroll
      for (int r = 0; r < 4; ++r) {
        int qq = row0 + r;
        if (qq < n_query) out[qq] = 1.0f / (1.0f + __expf(-(part[r] + bd3s)));
      }
    }
  }
}

extern "C" void kernel_launch(void* const* d_in, const int* in_sizes, int n_in,
                              void* d_out, int out_size, void* d_ws, size_t ws_size,
                              hipStream_t stream) {
  const float* x    = (const float*)d_in[0];
  const int*   ei   = (const int*)d_in[1];
  const int*   qe   = (const int*)d_in[2];
  const float* W1   = (const float*)d_in[3];
  const float* b1   = (const float*)d_in[4];
  const float* W2   = (const float*)d_in[5];
  const float* b2   = (const float*)d_in[6];
  const float* Wfc  = (const float*)d_in[7];
  const float* bfc  = (const float*)d_in[8];
  const float* Wd1  = (const float*)d_in[9];
  const float* bd1  = (const float*)d_in[10];
  const float* Wd2  = (const float*)d_in[11];
  const float* bd2  = (const float*)d_in[12];
  const float* Wd3  = (const float*)d_in[13];
  const float* bd3  = (const float*)d_in[14];
  float* out = (float*)d_out;

  const int n_nodes = in_sizes[0] / 7;
  const int n_edges = in_sizes[1] / 2;
  const int n_query = in_sizes[2] / 2;
  const int* e_src = ei;
  const int* e_dst = ei + n_edges;
  const int* q_src = qe;
  const int* q_dst = qe + n_query;

  const int n_blk1 = cdiv(n_edges, EPB);
  const int bh_len = NB * n_blk1;
  const int n_bucket = cdiv(n_nodes, NPB);

  // ---- workspace layout ----
  char* wp = (char*)d_ws;
  auto take = [&](size_t bytes) { char* p = wp; wp += (bytes + 255) & ~size_t(255); return p; };
  float* dinv    = (float*)take((size_t)n_nodes * 4);
  int*   counts  = (int*)  take((size_t)n_nodes * 4);
  int*   rowptr  = (int*)  take((size_t)(n_nodes + 1) * 4);
  int*   bsum    = (int*)  take(512 * 4);
  int*   bh      = (int*)  take((size_t)(bh_len + 1) * 4);
  int*   eoff    = (int*)  take((size_t)(bh_len + 1) * 4);
  unsigned int* ebuf = (unsigned int*)take((size_t)n_edges * 4);
  int*   csr_src = (int*)  take((size_t)n_edges * 4);
  float* aggx    = (float*)take((size_t)n_nodes * 8 * 4);
  float* W1p     = (float*)take(8 * 128 * 4);
  unsigned short* W2T   = (unsigned short*)take(128 * 128 * 2);
  unsigned short* WcaT  = (unsigned short*)take(128 * 128 * 2);
  unsigned short* WcbT  = (unsigned short*)take(128 * 128 * 2);
  float* bca     = (float*)take(128 * 4);
  float* bcb     = (float*)take(128 * 4);
  float* bufP    = (float*)take((size_t)n_nodes * 128 * 4);
  float* bufQ    = (float*)take((size_t)n_nodes * 128 * 4);
  float* bufR    = (float*)take((size_t)n_nodes * 64 * 4);

  const int mm_blocks = cdiv(n_nodes, 64);
  const int node_blocks = cdiv(n_nodes, TPB);
  const int scan_blocks = cdiv(n_nodes, SCAN_B);
  const int escan_blocks = cdiv(bh_len, SCAN_B);
  const int mfma_blocks = min(1024, cdiv(cdiv(n_nodes, 16), 4));

  // ---- CSR build (no global atomics): 8 dispatches ----
  bucket_hist_kernel<<<n_blk1, TPB, 0, stream>>>(e_dst, bh, n_edges, n_blk1);
  scan_block_kernel<<<escan_blocks, SCAN_B, 0, stream>>>(bh, eoff, bsum, bh_len);
  scan_fin_kernel<<<cdiv(bh_len, TPB), TPB, 0, stream>>>(eoff, bsum, escan_blocks, bh_len, n_edges);
  bucket_scatter_kernel<<<n_blk1, TPB, 0, stream>>>(e_src, e_dst, eoff, ebuf, n_edges, n_blk1);
  node_hist_kernel<<<n_bucket, TPB, 0, stream>>>(ebuf, eoff, counts, dinv, n_blk1, n_nodes);
  scan_block_kernel<<<scan_blocks, SCAN_B, 0, stream>>>(counts, rowptr, bsum, n_nodes);
  scan_fin_kernel<<<node_blocks, TPB, 0, stream>>>(rowptr, bsum, scan_blocks, n_nodes, n_edges);
  final_scatter_kernel<<<n_bucket, TPB, 0, stream>>>(ebuf, eoff, rowptr, csr_src, n_blk1, n_nodes);

  // ---- prep ----
  prep_weights_kernel<<<129, TPB, 0, stream>>>(W1, W2, Wfc, bfc, Wd1, bd1,
                                               W1p, W2T, WcaT, WcbT, bca, bcb);

  // ---- layer 1: aggx = A_hat x ; h1s(bf16) = relu(aggx @ W1p + b1) * dinv ----
  agg_x_kernel<<<cdiv(n_nodes * 8, TPB), TPB, 0, stream>>>(rowptr, csr_src, dinv, x, aggx, n_nodes);
  mm_tiled<8, 128><<<mm_blocks, TPB, 0, stream>>>(aggx, W1p, b1, dinv, (unsigned short*)bufP, n_nodes);
  // bufP = h1s (bf16, prescaled)

  // ---- layer 2 (split): g1 -> h2 ----
  gather4_kernel<<<cdiv(n_nodes * 64, TPB), TPB, 0, stream>>>(rowptr, csr_src, dinv,
                                                              (const uint4*)bufP, (uint4*)bufQ, n_nodes);
  mm_mfma<128, 128><<<mfma_blocks, TPB, 0, stream>>>((const unsigned short*)bufQ, W2T, b2,
                                                     (unsigned short*)bufR, n_nodes, 1);
  // bufR = h2 (bf16)

  // ---- decoder tables (fc folded, dual): atab = h2@Wca + bca ; btab = h2@Wcb + bcb ----
  unsigned short* atab = (unsigned short*)bufP;
  unsigned short* btab = (unsigned short*)bufQ;
  mm_mfma_dual_kernel<<<mfma_blocks, TPB, 0, stream>>>((const unsigned short*)bufR, WcaT, WcbT,
                                                       bca, bcb, atab, btab, n_nodes);

  // ---- per-query decode (MFMA) ----
  decoder_mfma_kernel<<<2048, TPB, 0, stream>>>(q_src, q_dst, atab, btab, Wd2, bd2, Wd3, bd3, out, n_query);
}